// Round 6
// baseline (30.930 us; speedup 1.0000x reference)
//
#include <hip/hip_runtime.h>

// TrafficNetworkDQN fused forward via fp16 MFMA (gfx950).
//
// All layers computed TRANSPOSED:  Act_out[n, m] = W^T[n,k] @ Act_in[k, m] + b[n]
// with positions m on the MFMA *N* dimension: the C/D fragment layout
// (col = lane&15 = m, row = 4*(lane>>4)+reg = n) equals the next layer's
// B fragment layout, so layer transitions are in-lane relu+cvt only.
//
// R6: fragment construction hoisted into a tiny setup kernel (1 wave) that
// writes the 15 half4 weight fragments + 9 float4 bias fragments per lane
// to d_ws in [frag][lane] layout. The main kernel's per-wave prologue drops
// from ~60 scattered loads + ~60 cvt/pack (~2000 cyc, diagnosed as the
// dominant fixed cost in R5) to 24 coalesced L2-hot loads (~300 cyc).
// Main loop: R5's proven 2-way tile interleave + fmaxf/cvt_pkrtz relu.

#define BL_TOTAL (4096 * 256)

// d_ws layout: 15 half4 frags at f*512 + lane*8, then 9 float4 biases at
// 7680 + b*1024 + lane*16.  Total 16,896 bytes.
#define WS_FRAG(ws, f)  (reinterpret_cast<half4*>((char*)(ws) + (f) * 512))
#define WS_BIAS(ws, b)  (reinterpret_cast<floatx4*>((char*)(ws) + 7680 + (b) * 1024))
#define WS_FRAG_C(ws, f) (reinterpret_cast<const half4*>((const char*)(ws) + (f) * 512))
#define WS_BIAS_C(ws, b) (reinterpret_cast<const floatx4*>((const char*)(ws) + 7680 + (b) * 1024))

typedef _Float16 half4   __attribute__((ext_vector_type(4)));
typedef __fp16   fp16x2  __attribute__((ext_vector_type(2)));
typedef float    floatx4 __attribute__((ext_vector_type(4)));

#define MFMA16(A, B, C) __builtin_amdgcn_mfma_f32_16x16x16f16((A), (B), (C), 0, 0, 0)

static __device__ __forceinline__ half4 relu_pack(floatx4 c) {
    float a0 = fmaxf(c[0], 0.0f), a1 = fmaxf(c[1], 0.0f);
    float a2 = fmaxf(c[2], 0.0f), a3 = fmaxf(c[3], 0.0f);
    fp16x2 lo = __builtin_amdgcn_cvt_pkrtz(a0, a1);
    fp16x2 hi = __builtin_amdgcn_cvt_pkrtz(a2, a3);
    half4 r;
    r[0] = (_Float16)lo[0]; r[1] = (_Float16)lo[1];
    r[2] = (_Float16)hi[0]; r[3] = (_Float16)hi[1];
    return r;
}

static __device__ __forceinline__ half4 pack4_rne(float a, float b, float c, float d) {
    half4 r; r[0] = (_Float16)a; r[1] = (_Float16)b; r[2] = (_Float16)c; r[3] = (_Float16)d;
    return r;
}

// ---------------- setup kernel: 1 block x 64 threads ----------------
__global__ void dqn_setup(
    const float* __restrict__ le_w1, const float* __restrict__ le_b1,
    const float* __restrict__ le_w2, const float* __restrict__ le_b2,
    const float* __restrict__ ls_w1, const float* __restrict__ ls_b1,
    const float* __restrict__ ls_w2, const float* __restrict__ ls_b2,
    const float* __restrict__ ls_w3, const float* __restrict__ ls_b3,
    const float* __restrict__ as_w1, const float* __restrict__ as_b1,
    const float* __restrict__ as_w2, const float* __restrict__ as_b2,
    const float* __restrict__ as_w3, const float* __restrict__ as_b3,
    void* __restrict__ ws)
{
    const int lane = threadIdx.x;   // 0..63
    const int m16  = lane & 15;
    const int g    = lane >> 4;
    const int k0   = g * 4;

    WS_FRAG(ws, 0)[lane] = pack4_rne(
        (k0 + 0 < 5) ? le_w1[(k0 + 0) * 16 + m16] : 0.0f,
        (k0 + 1 < 5) ? le_w1[(k0 + 1) * 16 + m16] : 0.0f,
        (k0 + 2 < 5) ? le_w1[(k0 + 2) * 16 + m16] : 0.0f,
        (k0 + 3 < 5) ? le_w1[(k0 + 3) * 16 + m16] : 0.0f);
    WS_FRAG(ws, 1)[lane] = pack4_rne(
        (m16 < 8) ? le_w2[(k0 + 0) * 8 + m16] : 0.0f,
        (m16 < 8) ? le_w2[(k0 + 1) * 8 + m16] : 0.0f,
        (m16 < 8) ? le_w2[(k0 + 2) * 8 + m16] : 0.0f,
        (m16 < 8) ? le_w2[(k0 + 3) * 8 + m16] : 0.0f);
    WS_FRAG(ws, 2)[lane] = pack4_rne(ls_w1[(k0+0)*32 + m16],      ls_w1[(k0+1)*32 + m16],
                                     ls_w1[(k0+2)*32 + m16],      ls_w1[(k0+3)*32 + m16]);
    WS_FRAG(ws, 3)[lane] = pack4_rne(ls_w1[(k0+0)*32 + 16 + m16], ls_w1[(k0+1)*32 + 16 + m16],
                                     ls_w1[(k0+2)*32 + 16 + m16], ls_w1[(k0+3)*32 + 16 + m16]);
    WS_FRAG(ws, 4)[lane] = pack4_rne(as_w1[(k0+0)*32 + m16],      as_w1[(k0+1)*32 + m16],
                                     as_w1[(k0+2)*32 + m16],      as_w1[(k0+3)*32 + m16]);
    WS_FRAG(ws, 5)[lane] = pack4_rne(as_w1[(k0+0)*32 + 16 + m16], as_w1[(k0+1)*32 + 16 + m16],
                                     as_w1[(k0+2)*32 + 16 + m16], as_w1[(k0+3)*32 + 16 + m16]);
    WS_FRAG(ws, 6)[lane] = pack4_rne(ls_w2[(k0+0)*16 + m16],      ls_w2[(k0+1)*16 + m16],
                                     ls_w2[(k0+2)*16 + m16],      ls_w2[(k0+3)*16 + m16]);
    WS_FRAG(ws, 7)[lane] = pack4_rne(ls_w2[(16+k0+0)*16 + m16],   ls_w2[(16+k0+1)*16 + m16],
                                     ls_w2[(16+k0+2)*16 + m16],   ls_w2[(16+k0+3)*16 + m16]);
    WS_FRAG(ws, 8)[lane] = pack4_rne(as_w2[(k0+0)*16 + m16],      as_w2[(k0+1)*16 + m16],
                                     as_w2[(k0+2)*16 + m16],      as_w2[(k0+3)*16 + m16]);
    WS_FRAG(ws, 9)[lane] = pack4_rne(as_w2[(16+k0+0)*16 + m16],   as_w2[(16+k0+1)*16 + m16],
                                     as_w2[(16+k0+2)*16 + m16],   as_w2[(16+k0+3)*16 + m16]);
    WS_FRAG(ws, 10)[lane] = pack4_rne(
        (m16 == 0) ? ls_w3[k0 + 0] : 0.0f,
        (m16 == 0) ? ls_w3[k0 + 1] : 0.0f,
        (m16 == 0) ? ls_w3[k0 + 2] : 0.0f,
        (m16 == 0) ? ls_w3[k0 + 3] : 0.0f);
    WS_FRAG(ws, 11)[lane] = pack4_rne(
        (m16 == 1) ? as_w3[(k0+0)*2] : ((m16 == 2) ? as_w3[(k0+0)*2 + 1] : 0.0f),
        (m16 == 1) ? as_w3[(k0+1)*2] : ((m16 == 2) ? as_w3[(k0+1)*2 + 1] : 0.0f),
        (m16 == 1) ? as_w3[(k0+2)*2] : ((m16 == 2) ? as_w3[(k0+2)*2 + 1] : 0.0f),
        (m16 == 1) ? as_w3[(k0+3)*2] : ((m16 == 2) ? as_w3[(k0+3)*2 + 1] : 0.0f));

    const int n0 = 4 * g;
    floatx4 bias1, bias2, bias3_0, bias3_1, bias3_2, bias3_3, bias4ls, bias4as, bias5;
    #pragma unroll
    for (int r = 0; r < 4; ++r) {
        bias1[r]   = le_b1[n0 + r];
        bias2[r]   = (n0 + r < 8) ? le_b2[n0 + r] : 0.0f;
        bias3_0[r] = ls_b1[n0 + r];
        bias3_1[r] = ls_b1[16 + n0 + r];
        bias3_2[r] = as_b1[n0 + r];
        bias3_3[r] = as_b1[16 + n0 + r];
        bias4ls[r] = ls_b2[n0 + r];
        bias4as[r] = as_b2[n0 + r];
        bias5[r]   = 0.0f;
    }
    if (g == 0 && m16 < 16) { bias5[0] = ls_b3[0]; bias5[1] = as_b3[0]; bias5[2] = as_b3[1]; }
    WS_BIAS(ws, 0)[lane] = bias1;
    WS_BIAS(ws, 1)[lane] = bias2;
    WS_BIAS(ws, 2)[lane] = bias3_0;
    WS_BIAS(ws, 3)[lane] = bias3_1;
    WS_BIAS(ws, 4)[lane] = bias3_2;
    WS_BIAS(ws, 5)[lane] = bias3_3;
    WS_BIAS(ws, 6)[lane] = bias4ls;
    WS_BIAS(ws, 7)[lane] = bias4as;
    WS_BIAS(ws, 8)[lane] = bias5;
}

// ---------------- main kernel ----------------
__global__ __launch_bounds__(256, 4) void dqn_mfma(
    const float* __restrict__ lf,    // [BL,5]
    const int*   __restrict__ ss,    // [BL]
    const float* __restrict__ emb,   // 8x8
    const void*  __restrict__ ws,    // packed fragments from dqn_setup
    float* __restrict__ out)         // [BL] scores, then [BL,2] action values
{
    const int lane = threadIdx.x & 63;
    const int wave = threadIdx.x >> 6;
    const int m16  = lane & 15;
    const int g    = lane >> 4;

    // ---- stage emb table to LDS as fp16 [8][8] ----
    __shared__ _Float16 embLDS[64];
    if (threadIdx.x < 64) embLDS[threadIdx.x] = (_Float16)emb[threadIdx.x];
    __syncthreads();

    // ---- coalesced fragment loads (L2-hot broadcast, 24 loads) ----
    const half4 a1    = WS_FRAG_C(ws, 0)[lane];
    const half4 a2    = WS_FRAG_C(ws, 1)[lane];
    const half4 a3_0  = WS_FRAG_C(ws, 2)[lane];
    const half4 a3_1  = WS_FRAG_C(ws, 3)[lane];
    const half4 a3_2  = WS_FRAG_C(ws, 4)[lane];
    const half4 a3_3  = WS_FRAG_C(ws, 5)[lane];
    const half4 a4ls0 = WS_FRAG_C(ws, 6)[lane];
    const half4 a4ls1 = WS_FRAG_C(ws, 7)[lane];
    const half4 a4as0 = WS_FRAG_C(ws, 8)[lane];
    const half4 a4as1 = WS_FRAG_C(ws, 9)[lane];
    const half4 a5a   = WS_FRAG_C(ws, 10)[lane];
    const half4 a5b   = WS_FRAG_C(ws, 11)[lane];
    const floatx4 bias1   = WS_BIAS_C(ws, 0)[lane];
    const floatx4 bias2   = WS_BIAS_C(ws, 1)[lane];
    const floatx4 bias3_0 = WS_BIAS_C(ws, 2)[lane];
    const floatx4 bias3_1 = WS_BIAS_C(ws, 3)[lane];
    const floatx4 bias3_2 = WS_BIAS_C(ws, 4)[lane];
    const floatx4 bias3_3 = WS_BIAS_C(ws, 5)[lane];
    const floatx4 bias4ls = WS_BIAS_C(ws, 6)[lane];
    const floatx4 bias4as = WS_BIAS_C(ws, 7)[lane];
    const floatx4 bias5   = WS_BIAS_C(ws, 8)[lane];

    // ---- main loop: 8 tiles per wave, 2 independent chains per iteration ----
    const int tile0 = blockIdx.x * 32 + wave * 8;
    float* __restrict__ out2 = out + BL_TOTAL;

    for (int t = 0; t < 8; t += 2) {
        const int posA = (tile0 + t) * 16 + m16;
        const int posB = posA + 16;

        float ax0 = 0.0f, ax1 = 0.0f, ax2 = 0.0f, ax3 = 0.0f;
        float bx0 = 0.0f, bx1 = 0.0f, bx2 = 0.0f, bx3 = 0.0f;
        if (g == 0) {
            ax0 = lf[posA * 5 + 0]; ax1 = lf[posA * 5 + 1];
            ax2 = lf[posA * 5 + 2]; ax3 = lf[posA * 5 + 3];
            bx0 = lf[posB * 5 + 0]; bx1 = lf[posB * 5 + 1];
            bx2 = lf[posB * 5 + 2]; bx3 = lf[posB * 5 + 3];
        } else if (g == 1) {
            ax0 = lf[posA * 5 + 4];
            bx0 = lf[posB * 5 + 4];
        }
        const int sA = ss[posA];
        const int sB = ss[posB];
        half4 evA = *reinterpret_cast<const half4*>(&embLDS[sA * 8 + (g & 1) * 4]);
        half4 evB = *reinterpret_cast<const half4*>(&embLDS[sB * 8 + (g & 1) * 4]);

        half4 b1A = pack4_rne(ax0, ax1, ax2, ax3);
        half4 b1B = pack4_rne(bx0, bx1, bx2, bx3);

        floatx4 c1A = MFMA16(a1, b1A, bias1);
        floatx4 c1B = MFMA16(a1, b1B, bias1);
        half4 h1A = relu_pack(c1A);
        half4 h1B = relu_pack(c1B);

        floatx4 c2A = MFMA16(a2, h1A, bias2);
        floatx4 c2B = MFMA16(a2, h1B, bias2);
        half4 b3A = relu_pack(c2A);
        half4 b3B = relu_pack(c2B);
        if (g >= 2) { b3A = evA; b3B = evB; }

        floatx4 c30A = MFMA16(a3_0, b3A, bias3_0);
        floatx4 c30B = MFMA16(a3_0, b3B, bias3_0);
        floatx4 c31A = MFMA16(a3_1, b3A, bias3_1);
        floatx4 c31B = MFMA16(a3_1, b3B, bias3_1);
        floatx4 c32A = MFMA16(a3_2, b3A, bias3_2);
        floatx4 c32B = MFMA16(a3_2, b3B, bias3_2);
        floatx4 c33A = MFMA16(a3_3, b3A, bias3_3);
        floatx4 c33B = MFMA16(a3_3, b3B, bias3_3);
        half4 g0A = relu_pack(c30A), g1A = relu_pack(c31A);
        half4 g2A = relu_pack(c32A), g3A = relu_pack(c33A);
        half4 g0B = relu_pack(c30B), g1B = relu_pack(c31B);
        half4 g2B = relu_pack(c32B), g3B = relu_pack(c33B);

        floatx4 clsA = MFMA16(a4ls1, g1A, MFMA16(a4ls0, g0A, bias4ls));
        floatx4 clsB = MFMA16(a4ls1, g1B, MFMA16(a4ls0, g0B, bias4ls));
        floatx4 casA = MFMA16(a4as1, g3A, MFMA16(a4as0, g2A, bias4as));
        floatx4 casB = MFMA16(a4as1, g3B, MFMA16(a4as0, g2B, bias4as));
        half4 hlsA = relu_pack(clsA), hasA = relu_pack(casA);
        half4 hlsB = relu_pack(clsB), hasB = relu_pack(casB);

        floatx4 c5A = MFMA16(a5b, hasA, MFMA16(a5a, hlsA, bias5));
        floatx4 c5B = MFMA16(a5b, hasB, MFMA16(a5a, hlsB, bias5));

        if (g == 0) {
            out[posA] = c5A[0];
            out[posB] = c5B[0];
            reinterpret_cast<float2*>(out2)[posA] = make_float2(c5A[1], c5A[2]);
            reinterpret_cast<float2*>(out2)[posB] = make_float2(c5B[1], c5B[2]);
        }
    }
}

extern "C" void kernel_launch(void* const* d_in, const int* in_sizes, int n_in,
                              void* d_out, int out_size, void* d_ws, size_t ws_size,
                              hipStream_t stream) {
    const float* lf    = (const float*)d_in[0];
    const int*   ss    = (const int*)  d_in[1];
    const float* le_w1 = (const float*)d_in[2];
    const float* le_b1 = (const float*)d_in[3];
    const float* le_w2 = (const float*)d_in[4];
    const float* le_b2 = (const float*)d_in[5];
    const float* emb   = (const float*)d_in[6];
    const float* ls_w1 = (const float*)d_in[7];
    const float* ls_b1 = (const float*)d_in[8];
    const float* ls_w2 = (const float*)d_in[9];
    const float* ls_b2 = (const float*)d_in[10];
    const float* ls_w3 = (const float*)d_in[11];
    const float* ls_b3 = (const float*)d_in[12];
    const float* as_w1 = (const float*)d_in[13];
    const float* as_b1 = (const float*)d_in[14];
    const float* as_w2 = (const float*)d_in[15];
    const float* as_b2 = (const float*)d_in[16];
    const float* as_w3 = (const float*)d_in[17];
    const float* as_b3 = (const float*)d_in[18];
    float* out = (float*)d_out;

    dqn_setup<<<1, 64, 0, stream>>>(
        le_w1, le_b1, le_w2, le_b2,
        ls_w1, ls_b1, ls_w2, ls_b2, ls_w3, ls_b3,
        as_w1, as_b1, as_w2, as_b2, as_w3, as_b3, d_ws);

    // 2048 blocks x 4 waves x 8 tiles x 16 positions = 1,048,576
    dqn_mfma<<<2048, 256, 0, stream>>>(lf, ss, emb, d_ws, out);
}